// Round 1
// baseline (143.989 us; speedup 1.0000x reference)
//
#include <hip/hip_runtime.h>

#define S 128
#define NB 8            // row-bands per plane
#define BAND (S / NB)   // 16 rows per band
#define NPLANES 1024    // B*C

struct Win { float m[6]; };   // [left | v.x v.y v.z v.w | right]

__device__ __forceinline__ Win load_win(const float* __restrict__ xp, int rr,
                                        int lane32, int tid64) {
    float4 v;
    if (rr >= 0 && rr < S) {
        v = *reinterpret_cast<const float4*>(xp + rr * S + lane32 * 4);
    } else {
        v = make_float4(0.f, 0.f, 0.f, 0.f);
    }
    // horizontal halo from neighbor lanes; band edges are the zero pad
    float l = __shfl(v.w, (tid64 - 1) & 63, 64);
    float r = __shfl(v.x, (tid64 + 1) & 63, 64);
    if (lane32 == 0)  l = 0.f;
    if (lane32 == 31) r = 0.f;
    Win w;
    w.m[0] = l; w.m[1] = v.x; w.m[2] = v.y; w.m[3] = v.z; w.m[4] = v.w; w.m[5] = r;
    return w;
}

__global__ __launch_bounds__(256) void pairwise_potential_kernel(
    const float* __restrict__ x, const float* __restrict__ w1,
    const float* __restrict__ w2, float* __restrict__ out)
{
    const int tid    = threadIdx.x;
    const int hw     = tid >> 5;      // halfwave index in block (0..7)
    const int lane32 = tid & 31;
    const int tid64  = tid & 63;

    // g = plane*8 + band  → blockIdx.x == plane (8 halfwaves/block = 8 bands)
    const int g     = blockIdx.x * 8 + hw;
    const int plane = g >> 3;         // b*64 + c
    const int band  = g & 7;
    const int r0    = band * BAND;
    const int c     = plane & 63;

    const float* xp  = x   + (size_t)plane * (S * S);
    const float* w1p = w1  + (size_t)c     * (S * S);
    const float* w2p = w2  + (size_t)c     * (S * S);
    float*       op  = out + (size_t)plane * (S * S);
    const int colbase = lane32 * 4;

    // constants
    const float NL  = -0.72134752044f;   // -0.5 * log2(e)
    const float E1  = 0.60653065971f;    // exp(-0.5)        (d = 1)
    const float E2  = 0.49306869139f;    // exp(-sqrt(2)/2)  (d = sqrt2)
    const float W2C = 1.07298380550f;    // (4 + 4*sqrt(2)) / 9
    const float NINTH = 1.0f / 9.0f;

    Win R0 = load_win(xp, r0 - 1, lane32, tid64);
    Win R1 = load_win(xp, r0,     lane32, tid64);

    for (int h = r0; h < r0 + BAND; ++h) {
        Win R2 = load_win(xp, h + 1, lane32, tid64);
        const float4 w1v = *reinterpret_cast<const float4*>(w1p + h * S + colbase);
        const float4 w2v = *reinterpret_cast<const float4*>(w2p + h * S + colbase);
        const float* w1a = &w1v.x;
        const float* w2a = &w2v.x;

        float4 o;
        float* ov = &o.x;
        #pragma unroll
        for (int k = 0; k < 4; ++k) {
            const float cen = R0.m[k];           // X(h-1, w-1): top-left of window
            // (0,0) term == exp(0) = 1 (skipped); 8 remaining exps
            float d, s1, s2;
            d  = cen - R0.m[k + 1]; s1  = exp2f(d * d * NL);
            d  = cen - R0.m[k + 2]; s1 += exp2f(d * d * NL);
            d  = cen - R1.m[k];     s1 += exp2f(d * d * NL);
            d  = cen - R2.m[k];     s1 += exp2f(d * d * NL);
            d  = cen - R1.m[k + 1]; s2  = exp2f(d * d * NL);
            d  = cen - R1.m[k + 2]; s2 += exp2f(d * d * NL);
            d  = cen - R2.m[k + 1]; s2 += exp2f(d * d * NL);
            d  = cen - R2.m[k + 2]; s2 += exp2f(d * d * NL);
            const float f = fmaf(E2, s2, fmaf(E1, s1, 1.0f));   // first-sum
            ov[k] = fmaf(w1a[k] * NINTH, f, w2a[k] * W2C);
        }
        *reinterpret_cast<float4*>(op + h * S + colbase) = o;
        R0 = R1; R1 = R2;
    }
}

extern "C" void kernel_launch(void* const* d_in, const int* in_sizes, int n_in,
                              void* d_out, int out_size, void* d_ws, size_t ws_size,
                              hipStream_t stream) {
    const float* x  = (const float*)d_in[0];
    const float* w1 = (const float*)d_in[1];
    const float* w2 = (const float*)d_in[2];
    float* out = (float*)d_out;
    // 1024 blocks (one plane each) x 256 threads (8 halfwave row-bands)
    pairwise_potential_kernel<<<NPLANES, 256, 0, stream>>>(x, w1, w2, out);
}